// Round 3
// baseline (71.122 us; speedup 1.0000x reference)
//
#include <hip/hip_runtime.h>

// Problem constants (match reference)
#define HH 256
#define WW 256
#define NB 2
#define NN 128
#define NSTEPS_K 50
#define RBLK ((HH * WW) / 256)   // 256 render blocks per batch
#define NPART (NB * RBLK)        // 512 partials

// ws layout (floats):
//   [0 .. 511]     partials
//   [512 .. 1023]  final nodes (2*128*2)
//   [1024]         counter (int, memset to 0 each call)
//   [2048 .. ]     gradient field: NB*HH*WW float2  (1 MB)
#define WS_GRAD_OFF_F 2048
#define WS_NEEDED_BYTES ((WS_GRAD_OFF_F + (size_t)NB * HH * WW * 2) * 4)

// ---------------- gradient-field precompute (massively parallel) -------------
__global__ void grad_kernel(const float* __restrict__ pred,
                            float2* __restrict__ g) {
    const int idx = blockIdx.x * 256 + threadIdx.x;  // 0 .. NB*H*W-1
    const int b = idx >> 16;
    const int pix = idx & 0xFFFF;
    const int i = pix >> 8, j = pix & (WW - 1);
    const float* f = pred + (b << 16);
    float gy, gx;
    if (i == 0)            gy = f[WW + j] - f[j];
    else if (i == HH - 1)  gy = f[(HH - 1) * WW + j] - f[(HH - 2) * WW + j];
    else                   gy = 0.5f * (f[(i + 1) * WW + j] - f[(i - 1) * WW + j]);
    if (j == 0)            gx = f[i * WW + 1] - f[i * WW];
    else if (j == WW - 1)  gx = f[i * WW + WW - 1] - f[i * WW + WW - 2];
    else                   gx = 0.5f * (f[i * WW + j + 1] - f[i * WW + j - 1]);
    g[idx] = make_float2(gy, gx);
}

// ---------------- evolve: 1 wave/batch, nodes in registers -------------------
// Lane l owns nodes 2l, 2l+1. Single shuffle round per step (neighbor
// POSITIONS), neighbors' d2 recomputed locally -> same arithmetic as the
// reference's two-stage d2/d4. Bilerp = 4 float2 loads per node.
__global__ __launch_bounds__(64, 1) void evolve2_kernel(
        const float2* __restrict__ g,
        const float* __restrict__ nodes_in,
        float* __restrict__ nodes_out) {
    const int b = blockIdx.x;
    const int l = threadIdx.x;            // 0..63
    const float2* gb = g + (b << 16);
    const int pl = (l + 63) & 63;
    const int nl = (l + 1) & 63;

    float4 nd = ((const float4*)nodes_in)[b * 64 + l];
    float y0n = nd.x, x0n = nd.y;         // node 2l
    float y1n = nd.z, x1n = nd.w;         // node 2l+1

    for (int s = 0; s < NSTEPS_K; ++s) {
        // ---- issue bilerp loads first (8 x dwordx2, overlap the DS round) ----
        float yca = fminf(fmaxf(y0n, 0.0f), 254.999f);
        float xca = fminf(fmaxf(x0n, 0.0f), 254.999f);
        int ra = (int)yca, ca = (int)xca;
        float wya = yca - (float)ra, wxa = xca - (float)ca;
        int basea = (ra << 8) + ca;
        float2 a00 = gb[basea],       a01 = gb[basea + 1];
        float2 a10 = gb[basea + WW],  a11 = gb[basea + WW + 1];

        float ycb = fminf(fmaxf(y1n, 0.0f), 254.999f);
        float xcb = fminf(fmaxf(x1n, 0.0f), 254.999f);
        int rb = (int)ycb, cb = (int)xcb;
        float wyb = ycb - (float)rb, wxb = xcb - (float)cb;
        int baseb = (rb << 8) + cb;
        float2 b00 = gb[baseb],       b01 = gb[baseb + 1];
        float2 b10 = gb[baseb + WW],  b11 = gb[baseb + WW + 1];

        // ---- single shuffle round: neighbor positions ----
        float pya = __shfl(y0n, pl), pxa = __shfl(x0n, pl);   // node 2l-2
        float pyb = __shfl(y1n, pl), pxb = __shfl(x1n, pl);   // node 2l-1
        float nya = __shfl(y0n, nl), nxa = __shfl(x0n, nl);   // node 2l+2
        float nyb = __shfl(y1n, nl), nxb = __shfl(x1n, nl);   // node 2l+3

        // d2[i] = (x[i+1] + x[i-1]) - 2 x[i]
        float d2ya = (y1n + pyb) - 2.0f * y0n;   // d2 of 2l
        float d2xa = (x1n + pxb) - 2.0f * x0n;
        float d2yb = (nya + y0n) - 2.0f * y1n;   // d2 of 2l+1
        float d2xb = (nxa + x0n) - 2.0f * x1n;
        float d2pyb = (y0n + pya) - 2.0f * pyb;  // d2 of 2l-1
        float d2pxb = (x0n + pxa) - 2.0f * pxb;
        float d2nya = (nyb + y1n) - 2.0f * nya;  // d2 of 2l+2
        float d2nxa = (nxb + x1n) - 2.0f * nxa;

        // d4[i] = (d2[i+1] + d2[i-1]) - 2 d2[i]
        float d4ya = (d2yb + d2pyb) - 2.0f * d2ya;
        float d4xa = (d2xb + d2pxb) - 2.0f * d2xa;
        float d4yb = (d2nya + d2ya) - 2.0f * d2yb;
        float d4xb = (d2nxa + d2xa) - 2.0f * d2xb;

        // ---- bilerp (reference term order) ----
        float ua = 1.0f - wya, va = 1.0f - wxa;
        float bya = a00.x * ua * va + a01.x * ua * wxa + a10.x * wya * va + a11.x * wya * wxa;
        float bxa = a00.y * ua * va + a01.y * ua * wxa + a10.y * wya * va + a11.y * wya * wxa;
        float ub = 1.0f - wyb, vb = 1.0f - wxb;
        float byb = b00.x * ub * vb + b01.x * ub * wxb + b10.x * wyb * vb + b11.x * wyb * wxb;
        float bxb = b00.y * ub * vb + b01.y * ub * wxb + b10.y * wyb * vb + b11.y * wyb * wxb;

        // x += STEPSZ*(ALPHA*d2 - BETA*d4 + ext); clip [0,255]
        y0n = y0n + 0.1f * ((0.01f * d2ya - 0.01f * d4ya) + (-10.0f * bya));
        x0n = x0n + 0.1f * ((0.01f * d2xa - 0.01f * d4xa) + (-10.0f * bxa));
        y1n = y1n + 0.1f * ((0.01f * d2yb - 0.01f * d4yb) + (-10.0f * byb));
        x1n = x1n + 0.1f * ((0.01f * d2xb - 0.01f * d4xb) + (-10.0f * bxb));
        y0n = fminf(fmaxf(y0n, 0.0f), 255.0f);
        x0n = fminf(fmaxf(x0n, 0.0f), 255.0f);
        y1n = fminf(fmaxf(y1n, 0.0f), 255.0f);
        x1n = fminf(fmaxf(x1n, 0.0f), 255.0f);
    }

    float4 out; out.x = y0n; out.y = x0n; out.z = y1n; out.w = x1n;
    ((float4*)nodes_out)[b * 64 + l] = out;
}

// ---------------- fallback evolve (direct pred sampling; ws too small) -------
__device__ __forceinline__ void sample_grad_direct(const float* __restrict__ f,
                                                   float y, float x,
                                                   float& by, float& bx) {
    float yc = fminf(fmaxf(y, 0.0f), 254.999f);
    float xc = fminf(fmaxf(x, 0.0f), 254.999f);
    int r0 = (int)yc, c0 = (int)xc;
    int r1 = r0 + 1, c1 = c0 + 1;
    float wy = yc - (float)r0, wx = xc - (float)c0;
    int rm = max(r0 - 1, 0), rp = min(r1 + 1, HH - 1);
    int cm = max(c0 - 1, 0), cp = min(c1 + 1, WW - 1);
    float sy0 = (r0 == 0) ? 1.0f : 0.5f;
    float sy1 = (r1 == HH - 1) ? 1.0f : 0.5f;
    float sx0 = (c0 == 0) ? 1.0f : 0.5f;
    float sx1 = (c1 == WW - 1) ? 1.0f : 0.5f;
    const float* fr0 = f + (r0 << 8);
    const float* fr1 = f + (r1 << 8);
    const float* frm = f + (rm << 8);
    const float* frp = f + (rp << 8);
    float f00 = fr0[c0], f01 = fr0[c1];
    float f10 = fr1[c0], f11 = fr1[c1];
    float f0m = fr0[cm], f0p = fr0[cp];
    float f1m = fr1[cm], f1p = fr1[cp];
    float fm0 = frm[c0], fm1 = frm[c1];
    float fp0 = frp[c0], fp1 = frp[c1];
    float gy00 = sy0 * (f10 - fm0), gy01 = sy0 * (f11 - fm1);
    float gy10 = sy1 * (fp0 - f00), gy11 = sy1 * (fp1 - f01);
    float gx00 = sx0 * (f01 - f0m), gx01 = sx1 * (f0p - f00);
    float gx10 = sx0 * (f11 - f1m), gx11 = sx1 * (f1p - f10);
    float u = 1.0f - wy, v = 1.0f - wx;
    by = gy00 * u * v + gy01 * u * wx + gy10 * wy * v + gy11 * wy * wx;
    bx = gx00 * u * v + gx01 * u * wx + gx10 * wy * v + gx11 * wy * wx;
}

__global__ __launch_bounds__(64, 1) void evolve_direct_kernel(
        const float* __restrict__ pred,
        const float* __restrict__ nodes_in,
        float* __restrict__ nodes_out) {
    const int b = blockIdx.x;
    const int l = threadIdx.x;
    const float* f = pred + b * HH * WW;
    const int pl = (l + 63) & 63;
    const int nl = (l + 1) & 63;
    float4 nd = ((const float4*)nodes_in)[b * 64 + l];
    float y0n = nd.x, x0n = nd.y, y1n = nd.z, x1n = nd.w;
    for (int s = 0; s < NSTEPS_K; ++s) {
        float by0, bx0, by1, bx1;
        sample_grad_direct(f, y0n, x0n, by0, bx0);
        sample_grad_direct(f, y1n, x1n, by1, bx1);
        float pya = __shfl(y0n, pl), pxa = __shfl(x0n, pl);
        float pyb = __shfl(y1n, pl), pxb = __shfl(x1n, pl);
        float nya = __shfl(y0n, nl), nxa = __shfl(x0n, nl);
        float nyb = __shfl(y1n, nl), nxb = __shfl(x1n, nl);
        float d2ya = (y1n + pyb) - 2.0f * y0n;
        float d2xa = (x1n + pxb) - 2.0f * x0n;
        float d2yb = (nya + y0n) - 2.0f * y1n;
        float d2xb = (nxa + x0n) - 2.0f * x1n;
        float d2pyb = (y0n + pya) - 2.0f * pyb;
        float d2pxb = (x0n + pxa) - 2.0f * pxb;
        float d2nya = (nyb + y1n) - 2.0f * nya;
        float d2nxa = (nxb + x1n) - 2.0f * nxa;
        float d4ya = (d2yb + d2pyb) - 2.0f * d2ya;
        float d4xa = (d2xb + d2pxb) - 2.0f * d2xa;
        float d4yb = (d2nya + d2ya) - 2.0f * d2yb;
        float d4xb = (d2nxa + d2xa) - 2.0f * d2xb;
        y0n = y0n + 0.1f * ((0.01f * d2ya - 0.01f * d4ya) + (-10.0f * by0));
        x0n = x0n + 0.1f * ((0.01f * d2xa - 0.01f * d4xa) + (-10.0f * bx0));
        y1n = y1n + 0.1f * ((0.01f * d2yb - 0.01f * d4yb) + (-10.0f * by1));
        x1n = x1n + 0.1f * ((0.01f * d2xb - 0.01f * d4xb) + (-10.0f * bx1));
        y0n = fminf(fmaxf(y0n, 0.0f), 255.0f);
        x0n = fminf(fmaxf(x0n, 0.0f), 255.0f);
        y1n = fminf(fmaxf(y1n, 0.0f), 255.0f);
        x1n = fminf(fmaxf(x1n, 0.0f), 255.0f);
    }
    float4 out; out.x = y0n; out.y = x0n; out.z = y1n; out.w = x1n;
    ((float4*)nodes_out)[b * 64 + l] = out;
}

// ---------------- render + deterministic last-block finalize -----------------
__global__ void render_kernel(const float* __restrict__ pred,
                              const float* __restrict__ nodes,
                              float* __restrict__ partials,
                              int* __restrict__ counter,
                              float* __restrict__ out) {
    const int b = blockIdx.y;
    const int chunk = blockIdx.x;    // 0..255
    const int tid = threadIdx.x;     // 0..255

    __shared__ float p0y[NN], p0x[NN], sdy[NN], sdx[NN], sidd[NN];
    if (tid < NN) {
        float ay = nodes[(b * NN + tid) * 2 + 0];
        float ax = nodes[(b * NN + tid) * 2 + 1];
        int j = (tid + 1) & (NN - 1);
        float cy = nodes[(b * NN + j) * 2 + 0];
        float cx = nodes[(b * NN + j) * 2 + 1];
        float ddy = cy - ay, ddx = cx - ax;
        p0y[tid] = ay; p0x[tid] = ax;
        sdy[tid] = ddy; sdx[tid] = ddx;
        sidd[tid] = 1.0f / (ddy * ddy + ddx * ddx + 1e-8f);
    }
    __syncthreads();

    const int pix = chunk * 256 + tid;
    const float qy = (float)(pix >> 8);
    const float qx = (float)(pix & (WW - 1));

    float minr2 = 1e30f;
#pragma unroll 8
    for (int s = 0; s < NN; ++s) {
        float qpy = qy - p0y[s];
        float qpx = qx - p0x[s];
        float t = (qpy * sdy[s] + qpx * sdx[s]) * sidd[s];
        t = fminf(fmaxf(t, 0.0f), 1.0f);
        float ry = qpy - t * sdy[s];
        float rx = qpx - t * sdx[s];
        float r2 = ry * ry + rx * rx;
        minr2 = fminf(minr2, r2);
    }
    float dist = fminf(sqrtf(minr2 + 1e-12f), 15.0f);
    float e = pred[b * HH * WW + pix] - dist;
    float se = e * e;

    for (int off = 32; off > 0; off >>= 1) se += __shfl_down(se, off);
    __shared__ float red[4];
    if ((tid & 63) == 0) red[tid >> 6] = se;
    __syncthreads();

    __shared__ int lastBlk;
    if (tid == 0) {
        float p = (red[0] + red[1]) + (red[2] + red[3]);
        __hip_atomic_store(&partials[b * RBLK + chunk], p,
                           __ATOMIC_RELEASE, __HIP_MEMORY_SCOPE_AGENT);
        int t = __hip_atomic_fetch_add(counter, 1,
                                       __ATOMIC_ACQ_REL, __HIP_MEMORY_SCOPE_AGENT);
        lastBlk = (t == NPART - 1);
    }
    __syncthreads();

    if (lastBlk) {   // fixed-order tree sum -> bit-deterministic regardless of which block is last
        float v = __hip_atomic_load(&partials[tid], __ATOMIC_RELAXED, __HIP_MEMORY_SCOPE_AGENT)
                + __hip_atomic_load(&partials[tid + 256], __ATOMIC_RELAXED, __HIP_MEMORY_SCOPE_AGENT);
        for (int off = 32; off > 0; off >>= 1) v += __shfl_down(v, off);
        __shared__ float red2[4];
        if ((tid & 63) == 0) red2[tid >> 6] = v;
        __syncthreads();
        if (tid == 0)
            out[0] = ((red2[0] + red2[1]) + (red2[2] + red2[3]))
                     * (1.0f / (float)(NB * HH * WW));
    }
}

extern "C" void kernel_launch(void* const* d_in, const int* in_sizes, int n_in,
                              void* d_out, int out_size, void* d_ws, size_t ws_size,
                              hipStream_t stream) {
    const float* pred = (const float*)d_in[0];    // (B,1,H,W) f32
    const float* nodes = (const float*)d_in[1];   // (B,N,2) f32
    float* ws = (float*)d_ws;
    float* partials = ws;                 // 512 f
    float* fnodes = ws + 512;             // 512 f
    int* counter = (int*)(ws + 1024);     // 1 int
    float2* gfield = (float2*)(ws + WS_GRAD_OFF_F);

    hipMemsetAsync(counter, 0, sizeof(int), stream);

    if (ws_size >= WS_NEEDED_BYTES) {
        grad_kernel<<<dim3(NB * HH * WW / 256), dim3(256), 0, stream>>>(pred, gfield);
        evolve2_kernel<<<dim3(NB), dim3(64), 0, stream>>>(gfield, nodes, fnodes);
    } else {
        evolve_direct_kernel<<<dim3(NB), dim3(64), 0, stream>>>(pred, nodes, fnodes);
    }
    render_kernel<<<dim3(RBLK, NB), dim3(256), 0, stream>>>(pred, fnodes, partials,
                                                            counter, (float*)d_out);
}

// Round 4
// 69.306 us; speedup vs baseline: 1.0262x; 1.0262x over previous
//
#include <hip/hip_runtime.h>

// Problem constants (match reference)
#define HH 256
#define WW 256
#define NB 2
#define NN 128
#define NSTEPS_K 50
#define RBLK ((HH * WW) / 256)   // 256 render blocks per batch
#define NPART (NB * RBLK)        // 512 partials

// ws layout (floats):
//   [0 .. 511]     partials
//   [512 .. 1023]  final nodes (2*128*2)
//   [1024]         counter (int; zeroed by grad/evolve_direct kernel each call)
//   [2048 .. ]     gradient field: NB*HH*WW float2  (1 MB)
#define WS_GRAD_OFF_F 2048
#define WS_NEEDED_BYTES ((WS_GRAD_OFF_F + (size_t)NB * HH * WW * 2) * 4)

// ---------------- gradient-field precompute (massively parallel) -------------
// Also zeroes the render completion counter (replaces a costly memset node).
__global__ void grad_kernel(const float* __restrict__ pred,
                            float2* __restrict__ g,
                            int* __restrict__ counter) {
    if (blockIdx.x == 0 && threadIdx.x == 0) {
        __hip_atomic_store(counter, 0, __ATOMIC_RELAXED, __HIP_MEMORY_SCOPE_AGENT);
    }
    const int idx = blockIdx.x * 256 + threadIdx.x;  // 0 .. NB*H*W-1
    const int b = idx >> 16;
    const int pix = idx & 0xFFFF;
    const int i = pix >> 8, j = pix & (WW - 1);
    const float* f = pred + (b << 16);
    float gy, gx;
    if (i == 0)            gy = f[WW + j] - f[j];
    else if (i == HH - 1)  gy = f[(HH - 1) * WW + j] - f[(HH - 2) * WW + j];
    else                   gy = 0.5f * (f[(i + 1) * WW + j] - f[(i - 1) * WW + j]);
    if (j == 0)            gx = f[i * WW + 1] - f[i * WW];
    else if (j == WW - 1)  gx = f[i * WW + WW - 1] - f[i * WW + WW - 2];
    else                   gx = 0.5f * (f[i * WW + j + 1] - f[i * WW + j - 1]);
    g[idx] = make_float2(gy, gx);
}

// ---------------- evolve: 1 wave/batch, nodes in registers -------------------
// Lane l owns nodes 2l, 2l+1. Single shuffle round per step (neighbor
// POSITIONS), neighbors' d2 recomputed locally -> same arithmetic as the
// reference's two-stage d2/d4. Bilerp = 4 float2 loads per node.
__global__ __launch_bounds__(64, 1) void evolve2_kernel(
        const float2* __restrict__ g,
        const float* __restrict__ nodes_in,
        float* __restrict__ nodes_out) {
    const int b = blockIdx.x;
    const int l = threadIdx.x;            // 0..63
    const float2* gb = g + (b << 16);
    const int pl = (l + 63) & 63;
    const int nl = (l + 1) & 63;

    float4 nd = ((const float4*)nodes_in)[b * 64 + l];
    float y0n = nd.x, x0n = nd.y;         // node 2l
    float y1n = nd.z, x1n = nd.w;         // node 2l+1

    for (int s = 0; s < NSTEPS_K; ++s) {
        // ---- issue bilerp loads first (8 x dwordx2, overlap the DS round) ----
        float yca = fminf(fmaxf(y0n, 0.0f), 254.999f);
        float xca = fminf(fmaxf(x0n, 0.0f), 254.999f);
        int ra = (int)yca, ca = (int)xca;
        float wya = yca - (float)ra, wxa = xca - (float)ca;
        int basea = (ra << 8) + ca;
        float2 a00 = gb[basea],       a01 = gb[basea + 1];
        float2 a10 = gb[basea + WW],  a11 = gb[basea + WW + 1];

        float ycb = fminf(fmaxf(y1n, 0.0f), 254.999f);
        float xcb = fminf(fmaxf(x1n, 0.0f), 254.999f);
        int rb = (int)ycb, cb = (int)xcb;
        float wyb = ycb - (float)rb, wxb = xcb - (float)cb;
        int baseb = (rb << 8) + cb;
        float2 b00 = gb[baseb],       b01 = gb[baseb + 1];
        float2 b10 = gb[baseb + WW],  b11 = gb[baseb + WW + 1];

        // ---- single shuffle round: neighbor positions ----
        float pya = __shfl(y0n, pl), pxa = __shfl(x0n, pl);   // node 2l-2
        float pyb = __shfl(y1n, pl), pxb = __shfl(x1n, pl);   // node 2l-1
        float nya = __shfl(y0n, nl), nxa = __shfl(x0n, nl);   // node 2l+2
        float nyb = __shfl(y1n, nl), nxb = __shfl(x1n, nl);   // node 2l+3

        // d2[i] = (x[i+1] + x[i-1]) - 2 x[i]
        float d2ya = (y1n + pyb) - 2.0f * y0n;   // d2 of 2l
        float d2xa = (x1n + pxb) - 2.0f * x0n;
        float d2yb = (nya + y0n) - 2.0f * y1n;   // d2 of 2l+1
        float d2xb = (nxa + x0n) - 2.0f * x1n;
        float d2pyb = (y0n + pya) - 2.0f * pyb;  // d2 of 2l-1
        float d2pxb = (x0n + pxa) - 2.0f * pxb;
        float d2nya = (nyb + y1n) - 2.0f * nya;  // d2 of 2l+2
        float d2nxa = (nxb + x1n) - 2.0f * nxa;

        // d4[i] = (d2[i+1] + d2[i-1]) - 2 d2[i]
        float d4ya = (d2yb + d2pyb) - 2.0f * d2ya;
        float d4xa = (d2xb + d2pxb) - 2.0f * d2xa;
        float d4yb = (d2nya + d2ya) - 2.0f * d2yb;
        float d4xb = (d2nxa + d2xa) - 2.0f * d2xb;

        // ---- bilerp (reference term order) ----
        float ua = 1.0f - wya, va = 1.0f - wxa;
        float bya = a00.x * ua * va + a01.x * ua * wxa + a10.x * wya * va + a11.x * wya * wxa;
        float bxa = a00.y * ua * va + a01.y * ua * wxa + a10.y * wya * va + a11.y * wya * wxa;
        float ub = 1.0f - wyb, vb = 1.0f - wxb;
        float byb = b00.x * ub * vb + b01.x * ub * wxb + b10.x * wyb * vb + b11.x * wyb * wxb;
        float bxb = b00.y * ub * vb + b01.y * ub * wxb + b10.y * wyb * vb + b11.y * wyb * wxb;

        // x += STEPSZ*(ALPHA*d2 - BETA*d4 + ext); clip [0,255]
        y0n = y0n + 0.1f * ((0.01f * d2ya - 0.01f * d4ya) + (-10.0f * bya));
        x0n = x0n + 0.1f * ((0.01f * d2xa - 0.01f * d4xa) + (-10.0f * bxa));
        y1n = y1n + 0.1f * ((0.01f * d2yb - 0.01f * d4yb) + (-10.0f * byb));
        x1n = x1n + 0.1f * ((0.01f * d2xb - 0.01f * d4xb) + (-10.0f * bxb));
        y0n = fminf(fmaxf(y0n, 0.0f), 255.0f);
        x0n = fminf(fmaxf(x0n, 0.0f), 255.0f);
        y1n = fminf(fmaxf(y1n, 0.0f), 255.0f);
        x1n = fminf(fmaxf(x1n, 0.0f), 255.0f);
    }

    float4 out; out.x = y0n; out.y = x0n; out.z = y1n; out.w = x1n;
    ((float4*)nodes_out)[b * 64 + l] = out;
}

// ---------------- fallback evolve (direct pred sampling; ws too small) -------
__device__ __forceinline__ void sample_grad_direct(const float* __restrict__ f,
                                                   float y, float x,
                                                   float& by, float& bx) {
    float yc = fminf(fmaxf(y, 0.0f), 254.999f);
    float xc = fminf(fmaxf(x, 0.0f), 254.999f);
    int r0 = (int)yc, c0 = (int)xc;
    int r1 = r0 + 1, c1 = c0 + 1;
    float wy = yc - (float)r0, wx = xc - (float)c0;
    int rm = max(r0 - 1, 0), rp = min(r1 + 1, HH - 1);
    int cm = max(c0 - 1, 0), cp = min(c1 + 1, WW - 1);
    float sy0 = (r0 == 0) ? 1.0f : 0.5f;
    float sy1 = (r1 == HH - 1) ? 1.0f : 0.5f;
    float sx0 = (c0 == 0) ? 1.0f : 0.5f;
    float sx1 = (c1 == WW - 1) ? 1.0f : 0.5f;
    const float* fr0 = f + (r0 << 8);
    const float* fr1 = f + (r1 << 8);
    const float* frm = f + (rm << 8);
    const float* frp = f + (rp << 8);
    float f00 = fr0[c0], f01 = fr0[c1];
    float f10 = fr1[c0], f11 = fr1[c1];
    float f0m = fr0[cm], f0p = fr0[cp];
    float f1m = fr1[cm], f1p = fr1[cp];
    float fm0 = frm[c0], fm1 = frm[c1];
    float fp0 = frp[c0], fp1 = frp[c1];
    float gy00 = sy0 * (f10 - fm0), gy01 = sy0 * (f11 - fm1);
    float gy10 = sy1 * (fp0 - f00), gy11 = sy1 * (fp1 - f01);
    float gx00 = sx0 * (f01 - f0m), gx01 = sx1 * (f0p - f00);
    float gx10 = sx0 * (f11 - f1m), gx11 = sx1 * (f1p - f10);
    float u = 1.0f - wy, v = 1.0f - wx;
    by = gy00 * u * v + gy01 * u * wx + gy10 * wy * v + gy11 * wy * wx;
    bx = gx00 * u * v + gx01 * u * wx + gx10 * wy * v + gx11 * wy * wx;
}

__global__ __launch_bounds__(64, 1) void evolve_direct_kernel(
        const float* __restrict__ pred,
        const float* __restrict__ nodes_in,
        float* __restrict__ nodes_out,
        int* __restrict__ counter) {
    const int b = blockIdx.x;
    const int l = threadIdx.x;
    if (b == 0 && l == 0) {
        __hip_atomic_store(counter, 0, __ATOMIC_RELAXED, __HIP_MEMORY_SCOPE_AGENT);
    }
    const float* f = pred + b * HH * WW;
    const int pl = (l + 63) & 63;
    const int nl = (l + 1) & 63;
    float4 nd = ((const float4*)nodes_in)[b * 64 + l];
    float y0n = nd.x, x0n = nd.y, y1n = nd.z, x1n = nd.w;
    for (int s = 0; s < NSTEPS_K; ++s) {
        float by0, bx0, by1, bx1;
        sample_grad_direct(f, y0n, x0n, by0, bx0);
        sample_grad_direct(f, y1n, x1n, by1, bx1);
        float pya = __shfl(y0n, pl), pxa = __shfl(x0n, pl);
        float pyb = __shfl(y1n, pl), pxb = __shfl(x1n, pl);
        float nya = __shfl(y0n, nl), nxa = __shfl(x0n, nl);
        float nyb = __shfl(y1n, nl), nxb = __shfl(x1n, nl);
        float d2ya = (y1n + pyb) - 2.0f * y0n;
        float d2xa = (x1n + pxb) - 2.0f * x0n;
        float d2yb = (nya + y0n) - 2.0f * y1n;
        float d2xb = (nxa + x0n) - 2.0f * x1n;
        float d2pyb = (y0n + pya) - 2.0f * pyb;
        float d2pxb = (x0n + pxa) - 2.0f * pxb;
        float d2nya = (nyb + y1n) - 2.0f * nya;
        float d2nxa = (nxb + x1n) - 2.0f * nxa;
        float d4ya = (d2yb + d2pyb) - 2.0f * d2ya;
        float d4xa = (d2xb + d2pxb) - 2.0f * d2xa;
        float d4yb = (d2nya + d2ya) - 2.0f * d2yb;
        float d4xb = (d2nxa + d2xa) - 2.0f * d2xb;
        y0n = y0n + 0.1f * ((0.01f * d2ya - 0.01f * d4ya) + (-10.0f * by0));
        x0n = x0n + 0.1f * ((0.01f * d2xa - 0.01f * d4xa) + (-10.0f * bx0));
        y1n = y1n + 0.1f * ((0.01f * d2yb - 0.01f * d4yb) + (-10.0f * by1));
        x1n = x1n + 0.1f * ((0.01f * d2xb - 0.01f * d4xb) + (-10.0f * bx1));
        y0n = fminf(fmaxf(y0n, 0.0f), 255.0f);
        x0n = fminf(fmaxf(x0n, 0.0f), 255.0f);
        y1n = fminf(fmaxf(y1n, 0.0f), 255.0f);
        x1n = fminf(fmaxf(x1n, 0.0f), 255.0f);
    }
    float4 out; out.x = y0n; out.y = x0n; out.z = y1n; out.w = x1n;
    ((float4*)nodes_out)[b * 64 + l] = out;
}

// ---------------- render + deterministic last-block finalize -----------------
__global__ void render_kernel(const float* __restrict__ pred,
                              const float* __restrict__ nodes,
                              float* __restrict__ partials,
                              int* __restrict__ counter,
                              float* __restrict__ out) {
    const int b = blockIdx.y;
    const int chunk = blockIdx.x;    // 0..255
    const int tid = threadIdx.x;     // 0..255

    __shared__ float p0y[NN], p0x[NN], sdy[NN], sdx[NN], sidd[NN];
    if (tid < NN) {
        float ay = nodes[(b * NN + tid) * 2 + 0];
        float ax = nodes[(b * NN + tid) * 2 + 1];
        int j = (tid + 1) & (NN - 1);
        float cy = nodes[(b * NN + j) * 2 + 0];
        float cx = nodes[(b * NN + j) * 2 + 1];
        float ddy = cy - ay, ddx = cx - ax;
        p0y[tid] = ay; p0x[tid] = ax;
        sdy[tid] = ddy; sdx[tid] = ddx;
        sidd[tid] = 1.0f / (ddy * ddy + ddx * ddx + 1e-8f);
    }
    __syncthreads();

    const int pix = chunk * 256 + tid;
    const float qy = (float)(pix >> 8);
    const float qx = (float)(pix & (WW - 1));

    float minr2 = 1e30f;
#pragma unroll 8
    for (int s = 0; s < NN; ++s) {
        float qpy = qy - p0y[s];
        float qpx = qx - p0x[s];
        float t = (qpy * sdy[s] + qpx * sdx[s]) * sidd[s];
        t = fminf(fmaxf(t, 0.0f), 1.0f);
        float ry = qpy - t * sdy[s];
        float rx = qpx - t * sdx[s];
        float r2 = ry * ry + rx * rx;
        minr2 = fminf(minr2, r2);
    }
    float dist = fminf(sqrtf(minr2 + 1e-12f), 15.0f);
    float e = pred[b * HH * WW + pix] - dist;
    float se = e * e;

    for (int off = 32; off > 0; off >>= 1) se += __shfl_down(se, off);
    __shared__ float red[4];
    if ((tid & 63) == 0) red[tid >> 6] = se;
    __syncthreads();

    __shared__ int lastBlk;
    if (tid == 0) {
        float p = (red[0] + red[1]) + (red[2] + red[3]);
        __hip_atomic_store(&partials[b * RBLK + chunk], p,
                           __ATOMIC_RELEASE, __HIP_MEMORY_SCOPE_AGENT);
        int t = __hip_atomic_fetch_add(counter, 1,
                                       __ATOMIC_ACQ_REL, __HIP_MEMORY_SCOPE_AGENT);
        lastBlk = (t == NPART - 1);
    }
    __syncthreads();

    if (lastBlk) {   // fixed-order tree sum -> bit-deterministic regardless of which block is last
        float v = __hip_atomic_load(&partials[tid], __ATOMIC_RELAXED, __HIP_MEMORY_SCOPE_AGENT)
                + __hip_atomic_load(&partials[tid + 256], __ATOMIC_RELAXED, __HIP_MEMORY_SCOPE_AGENT);
        for (int off = 32; off > 0; off >>= 1) v += __shfl_down(v, off);
        __shared__ float red2[4];
        if ((tid & 63) == 0) red2[tid >> 6] = v;
        __syncthreads();
        if (tid == 0)
            out[0] = ((red2[0] + red2[1]) + (red2[2] + red2[3]))
                     * (1.0f / (float)(NB * HH * WW));
    }
}

extern "C" void kernel_launch(void* const* d_in, const int* in_sizes, int n_in,
                              void* d_out, int out_size, void* d_ws, size_t ws_size,
                              hipStream_t stream) {
    const float* pred = (const float*)d_in[0];    // (B,1,H,W) f32
    const float* nodes = (const float*)d_in[1];   // (B,N,2) f32
    float* ws = (float*)d_ws;
    float* partials = ws;                 // 512 f
    float* fnodes = ws + 512;             // 512 f
    int* counter = (int*)(ws + 1024);     // 1 int (zeroed by first kernel)
    float2* gfield = (float2*)(ws + WS_GRAD_OFF_F);

    if (ws_size >= WS_NEEDED_BYTES) {
        grad_kernel<<<dim3(NB * HH * WW / 256), dim3(256), 0, stream>>>(pred, gfield, counter);
        evolve2_kernel<<<dim3(NB), dim3(64), 0, stream>>>(gfield, nodes, fnodes);
    } else {
        evolve_direct_kernel<<<dim3(NB), dim3(64), 0, stream>>>(pred, nodes, fnodes, counter);
    }
    render_kernel<<<dim3(RBLK, NB), dim3(256), 0, stream>>>(pred, fnodes, partials,
                                                            counter, (float*)d_out);
}

// Round 5
// 66.455 us; speedup vs baseline: 1.0702x; 1.0429x over previous
//
#include <hip/hip_runtime.h>

// Problem constants (match reference)
#define HH 256
#define WW 256
#define NB 2
#define NN 128
#define NSTEPS_K 50
#define RBLK ((HH * WW) / 256)   // 256 render blocks per batch
#define NPART (NB * RBLK)        // 512 partials

// ws layout (floats):
//   [0 .. 511]     partials
//   [512 .. 1023]  final nodes (2*128*2)
//   [1024]         counter (int; zeroed by evolve kernel each call)
//   [2048 .. ]     gradient field: NB*HH*WW float2  (1 MB)
#define WS_GRAD_OFF_F 2048
#define WS_NEEDED_BYTES ((WS_GRAD_OFF_F + (size_t)NB * HH * WW * 2) * 4)

// ---------------- fused gradient-gen + evolve ---------------------------------
// One block per batch, 1024 threads. Phase A: all 16 waves build the gradient
// field for THIS batch from THIS CU -> the 512 KB field lands dirty in the
// LOCAL XCD L2 (cross-kernel L2 reuse doesn't survive dispatch boundaries;
// in-kernel production guarantees local-L2 hits for the serial loop).
// Phase B: wave 0 runs the 50 strictly-serial active-contour steps; all field
// loads are local L1/L2 hits. Arithmetic is bit-identical to the reference
// (validated absmax == 0.0 in prior rounds -- do not reassociate).
__global__ __launch_bounds__(1024) void evolve_fused_kernel(
        const float* __restrict__ pred,
        const float* __restrict__ nodes_in,
        float* __restrict__ nodes_out,
        float2* __restrict__ g,
        int* __restrict__ counter) {
    const int b = blockIdx.x;
    const int tid = threadIdx.x;
    if (b == 0 && tid == 0) {
        __hip_atomic_store(counter, 0, __ATOMIC_RELAXED, __HIP_MEMORY_SCOPE_AGENT);
    }

    const float* f = pred + (b << 16);
    float2* gb = g + (b << 16);

    // ---- Phase A: gradient field (64 px per thread, lane-consecutive) ----
    // jnp.gradient, branchless via clamped indices + one-sided scale select;
    // interior 0.5*(f[i+1]-f[i-1]) and edge f[1]-f[0] are bit-exact vs ref.
    #pragma unroll 4
    for (int k = 0; k < 64; ++k) {
        int p = (k << 10) + tid;            // 0..65535
        int i = p >> 8, j = p & (WW - 1);
        int iu = max(i - 1, 0), id = min(i + 1, HH - 1);
        int jl = max(j - 1, 0), jr = min(j + 1, WW - 1);
        float sy = (i == 0 || i == HH - 1) ? 1.0f : 0.5f;
        float sx = (j == 0 || j == WW - 1) ? 1.0f : 0.5f;
        float gy = sy * (f[(id << 8) + j] - f[(iu << 8) + j]);
        float gx = sx * (f[(i << 8) + jr] - f[(i << 8) + jl]);
        gb[p] = make_float2(gy, gx);
    }
    __syncthreads();          // all field stores drained (vmcnt) + visible in L2
    if (tid >= 64) return;    // waves 1..15 done; wave 0 proceeds barrier-free

    // ---- Phase B: 1 wave, lane l owns nodes 2l and 2l+1 in registers ----
    const int l = tid;                    // 0..63
    const int pl = (l + 63) & 63;
    const int nl = (l + 1) & 63;

    float4 nd = ((const float4*)nodes_in)[b * 64 + l];
    float y0n = nd.x, x0n = nd.y;         // node 2l
    float y1n = nd.z, x1n = nd.w;         // node 2l+1

    for (int s = 0; s < NSTEPS_K; ++s) {
        // ---- issue bilerp loads first (8 x dwordx2, local L1/L2 hits) ----
        float yca = fminf(fmaxf(y0n, 0.0f), 254.999f);
        float xca = fminf(fmaxf(x0n, 0.0f), 254.999f);
        int ra = (int)yca, ca = (int)xca;
        float wya = yca - (float)ra, wxa = xca - (float)ca;
        int basea = (ra << 8) + ca;
        float2 a00 = gb[basea],       a01 = gb[basea + 1];
        float2 a10 = gb[basea + WW],  a11 = gb[basea + WW + 1];

        float ycb = fminf(fmaxf(y1n, 0.0f), 254.999f);
        float xcb = fminf(fmaxf(x1n, 0.0f), 254.999f);
        int rb = (int)ycb, cb = (int)xcb;
        float wyb = ycb - (float)rb, wxb = xcb - (float)cb;
        int baseb = (rb << 8) + cb;
        float2 b00 = gb[baseb],       b01 = gb[baseb + 1];
        float2 b10 = gb[baseb + WW],  b11 = gb[baseb + WW + 1];

        // ---- single shuffle round: neighbor positions ----
        float pya = __shfl(y0n, pl), pxa = __shfl(x0n, pl);   // node 2l-2
        float pyb = __shfl(y1n, pl), pxb = __shfl(x1n, pl);   // node 2l-1
        float nya = __shfl(y0n, nl), nxa = __shfl(x0n, nl);   // node 2l+2
        float nyb = __shfl(y1n, nl), nxb = __shfl(x1n, nl);   // node 2l+3

        // d2[i] = (x[i+1] + x[i-1]) - 2 x[i]
        float d2ya = (y1n + pyb) - 2.0f * y0n;   // d2 of 2l
        float d2xa = (x1n + pxb) - 2.0f * x0n;
        float d2yb = (nya + y0n) - 2.0f * y1n;   // d2 of 2l+1
        float d2xb = (nxa + x0n) - 2.0f * x1n;
        float d2pyb = (y0n + pya) - 2.0f * pyb;  // d2 of 2l-1
        float d2pxb = (x0n + pxa) - 2.0f * pxb;
        float d2nya = (nyb + y1n) - 2.0f * nya;  // d2 of 2l+2
        float d2nxa = (nxb + x1n) - 2.0f * nxa;

        // d4[i] = (d2[i+1] + d2[i-1]) - 2 d2[i]
        float d4ya = (d2yb + d2pyb) - 2.0f * d2ya;
        float d4xa = (d2xb + d2pxb) - 2.0f * d2xa;
        float d4yb = (d2nya + d2ya) - 2.0f * d2yb;
        float d4xb = (d2nxa + d2xa) - 2.0f * d2xb;

        // ---- bilerp (reference term order) ----
        float ua = 1.0f - wya, va = 1.0f - wxa;
        float bya = a00.x * ua * va + a01.x * ua * wxa + a10.x * wya * va + a11.x * wya * wxa;
        float bxa = a00.y * ua * va + a01.y * ua * wxa + a10.y * wya * va + a11.y * wya * wxa;
        float ub = 1.0f - wyb, vb = 1.0f - wxb;
        float byb = b00.x * ub * vb + b01.x * ub * wxb + b10.x * wyb * vb + b11.x * wyb * wxb;
        float bxb = b00.y * ub * vb + b01.y * ub * wxb + b10.y * wyb * vb + b11.y * wyb * wxb;

        // x += STEPSZ*(ALPHA*d2 - BETA*d4 + ext); clip [0,255]
        y0n = y0n + 0.1f * ((0.01f * d2ya - 0.01f * d4ya) + (-10.0f * bya));
        x0n = x0n + 0.1f * ((0.01f * d2xa - 0.01f * d4xa) + (-10.0f * bxa));
        y1n = y1n + 0.1f * ((0.01f * d2yb - 0.01f * d4yb) + (-10.0f * byb));
        x1n = x1n + 0.1f * ((0.01f * d2xb - 0.01f * d4xb) + (-10.0f * bxb));
        y0n = fminf(fmaxf(y0n, 0.0f), 255.0f);
        x0n = fminf(fmaxf(x0n, 0.0f), 255.0f);
        y1n = fminf(fmaxf(y1n, 0.0f), 255.0f);
        x1n = fminf(fmaxf(x1n, 0.0f), 255.0f);
    }

    float4 out; out.x = y0n; out.y = x0n; out.z = y1n; out.w = x1n;
    ((float4*)nodes_out)[b * 64 + l] = out;
}

// ---------------- fallback evolve (direct pred sampling; ws too small) -------
__device__ __forceinline__ void sample_grad_direct(const float* __restrict__ f,
                                                   float y, float x,
                                                   float& by, float& bx) {
    float yc = fminf(fmaxf(y, 0.0f), 254.999f);
    float xc = fminf(fmaxf(x, 0.0f), 254.999f);
    int r0 = (int)yc, c0 = (int)xc;
    int r1 = r0 + 1, c1 = c0 + 1;
    float wy = yc - (float)r0, wx = xc - (float)c0;
    int rm = max(r0 - 1, 0), rp = min(r1 + 1, HH - 1);
    int cm = max(c0 - 1, 0), cp = min(c1 + 1, WW - 1);
    float sy0 = (r0 == 0) ? 1.0f : 0.5f;
    float sy1 = (r1 == HH - 1) ? 1.0f : 0.5f;
    float sx0 = (c0 == 0) ? 1.0f : 0.5f;
    float sx1 = (c1 == WW - 1) ? 1.0f : 0.5f;
    const float* fr0 = f + (r0 << 8);
    const float* fr1 = f + (r1 << 8);
    const float* frm = f + (rm << 8);
    const float* frp = f + (rp << 8);
    float f00 = fr0[c0], f01 = fr0[c1];
    float f10 = fr1[c0], f11 = fr1[c1];
    float f0m = fr0[cm], f0p = fr0[cp];
    float f1m = fr1[cm], f1p = fr1[cp];
    float fm0 = frm[c0], fm1 = frm[c1];
    float fp0 = frp[c0], fp1 = frp[c1];
    float gy00 = sy0 * (f10 - fm0), gy01 = sy0 * (f11 - fm1);
    float gy10 = sy1 * (fp0 - f00), gy11 = sy1 * (fp1 - f01);
    float gx00 = sx0 * (f01 - f0m), gx01 = sx1 * (f0p - f00);
    float gx10 = sx0 * (f11 - f1m), gx11 = sx1 * (f1p - f10);
    float u = 1.0f - wy, v = 1.0f - wx;
    by = gy00 * u * v + gy01 * u * wx + gy10 * wy * v + gy11 * wy * wx;
    bx = gx00 * u * v + gx01 * u * wx + gx10 * wy * v + gx11 * wy * wx;
}

__global__ __launch_bounds__(64, 1) void evolve_direct_kernel(
        const float* __restrict__ pred,
        const float* __restrict__ nodes_in,
        float* __restrict__ nodes_out,
        int* __restrict__ counter) {
    const int b = blockIdx.x;
    const int l = threadIdx.x;
    if (b == 0 && l == 0) {
        __hip_atomic_store(counter, 0, __ATOMIC_RELAXED, __HIP_MEMORY_SCOPE_AGENT);
    }
    const float* f = pred + b * HH * WW;
    const int pl = (l + 63) & 63;
    const int nl = (l + 1) & 63;
    float4 nd = ((const float4*)nodes_in)[b * 64 + l];
    float y0n = nd.x, x0n = nd.y, y1n = nd.z, x1n = nd.w;
    for (int s = 0; s < NSTEPS_K; ++s) {
        float by0, bx0, by1, bx1;
        sample_grad_direct(f, y0n, x0n, by0, bx0);
        sample_grad_direct(f, y1n, x1n, by1, bx1);
        float pya = __shfl(y0n, pl), pxa = __shfl(x0n, pl);
        float pyb = __shfl(y1n, pl), pxb = __shfl(x1n, pl);
        float nya = __shfl(y0n, nl), nxa = __shfl(x0n, nl);
        float nyb = __shfl(y1n, nl), nxb = __shfl(x1n, nl);
        float d2ya = (y1n + pyb) - 2.0f * y0n;
        float d2xa = (x1n + pxb) - 2.0f * x0n;
        float d2yb = (nya + y0n) - 2.0f * y1n;
        float d2xb = (nxa + x0n) - 2.0f * x1n;
        float d2pyb = (y0n + pya) - 2.0f * pyb;
        float d2pxb = (x0n + pxa) - 2.0f * pxb;
        float d2nya = (nyb + y1n) - 2.0f * nya;
        float d2nxa = (nxb + x1n) - 2.0f * nxa;
        float d4ya = (d2yb + d2pyb) - 2.0f * d2ya;
        float d4xa = (d2xb + d2pxb) - 2.0f * d2xa;
        float d4yb = (d2nya + d2ya) - 2.0f * d2yb;
        float d4xb = (d2nxa + d2xa) - 2.0f * d2xb;
        y0n = y0n + 0.1f * ((0.01f * d2ya - 0.01f * d4ya) + (-10.0f * by0));
        x0n = x0n + 0.1f * ((0.01f * d2xa - 0.01f * d4xa) + (-10.0f * bx0));
        y1n = y1n + 0.1f * ((0.01f * d2yb - 0.01f * d4yb) + (-10.0f * by1));
        x1n = x1n + 0.1f * ((0.01f * d2xb - 0.01f * d4xb) + (-10.0f * bx1));
        y0n = fminf(fmaxf(y0n, 0.0f), 255.0f);
        x0n = fminf(fmaxf(x0n, 0.0f), 255.0f);
        y1n = fminf(fmaxf(y1n, 0.0f), 255.0f);
        x1n = fminf(fmaxf(x1n, 0.0f), 255.0f);
    }
    float4 out; out.x = y0n; out.y = x0n; out.z = y1n; out.w = x1n;
    ((float4*)nodes_out)[b * 64 + l] = out;
}

// ---------------- render + deterministic last-block finalize -----------------
__global__ void render_kernel(const float* __restrict__ pred,
                              const float* __restrict__ nodes,
                              float* __restrict__ partials,
                              int* __restrict__ counter,
                              float* __restrict__ out) {
    const int b = blockIdx.y;
    const int chunk = blockIdx.x;    // 0..255
    const int tid = threadIdx.x;     // 0..255

    __shared__ float p0y[NN], p0x[NN], sdy[NN], sdx[NN], sidd[NN];
    if (tid < NN) {
        float ay = nodes[(b * NN + tid) * 2 + 0];
        float ax = nodes[(b * NN + tid) * 2 + 1];
        int j = (tid + 1) & (NN - 1);
        float cy = nodes[(b * NN + j) * 2 + 0];
        float cx = nodes[(b * NN + j) * 2 + 1];
        float ddy = cy - ay, ddx = cx - ax;
        p0y[tid] = ay; p0x[tid] = ax;
        sdy[tid] = ddy; sdx[tid] = ddx;
        sidd[tid] = 1.0f / (ddy * ddy + ddx * ddx + 1e-8f);
    }
    __syncthreads();

    const int pix = chunk * 256 + tid;
    const float qy = (float)(pix >> 8);
    const float qx = (float)(pix & (WW - 1));

    float minr2 = 1e30f;
#pragma unroll 8
    for (int s = 0; s < NN; ++s) {
        float qpy = qy - p0y[s];
        float qpx = qx - p0x[s];
        float t = (qpy * sdy[s] + qpx * sdx[s]) * sidd[s];
        t = fminf(fmaxf(t, 0.0f), 1.0f);
        float ry = qpy - t * sdy[s];
        float rx = qpx - t * sdx[s];
        float r2 = ry * ry + rx * rx;
        minr2 = fminf(minr2, r2);
    }
    float dist = fminf(sqrtf(minr2 + 1e-12f), 15.0f);
    float e = pred[b * HH * WW + pix] - dist;
    float se = e * e;

    for (int off = 32; off > 0; off >>= 1) se += __shfl_down(se, off);
    __shared__ float red[4];
    if ((tid & 63) == 0) red[tid >> 6] = se;
    __syncthreads();

    __shared__ int lastBlk;
    if (tid == 0) {
        float p = (red[0] + red[1]) + (red[2] + red[3]);
        __hip_atomic_store(&partials[b * RBLK + chunk], p,
                           __ATOMIC_RELEASE, __HIP_MEMORY_SCOPE_AGENT);
        int t = __hip_atomic_fetch_add(counter, 1,
                                       __ATOMIC_ACQ_REL, __HIP_MEMORY_SCOPE_AGENT);
        lastBlk = (t == NPART - 1);
    }
    __syncthreads();

    if (lastBlk) {   // fixed-order tree sum -> bit-deterministic regardless of which block is last
        float v = __hip_atomic_load(&partials[tid], __ATOMIC_RELAXED, __HIP_MEMORY_SCOPE_AGENT)
                + __hip_atomic_load(&partials[tid + 256], __ATOMIC_RELAXED, __HIP_MEMORY_SCOPE_AGENT);
        for (int off = 32; off > 0; off >>= 1) v += __shfl_down(v, off);
        __shared__ float red2[4];
        if ((tid & 63) == 0) red2[tid >> 6] = v;
        __syncthreads();
        if (tid == 0)
            out[0] = ((red2[0] + red2[1]) + (red2[2] + red2[3]))
                     * (1.0f / (float)(NB * HH * WW));
    }
}

extern "C" void kernel_launch(void* const* d_in, const int* in_sizes, int n_in,
                              void* d_out, int out_size, void* d_ws, size_t ws_size,
                              hipStream_t stream) {
    const float* pred = (const float*)d_in[0];    // (B,1,H,W) f32
    const float* nodes = (const float*)d_in[1];   // (B,N,2) f32
    float* ws = (float*)d_ws;
    float* partials = ws;                 // 512 f
    float* fnodes = ws + 512;             // 512 f
    int* counter = (int*)(ws + 1024);     // 1 int (zeroed by evolve kernel)
    float2* gfield = (float2*)(ws + WS_GRAD_OFF_F);

    if (ws_size >= WS_NEEDED_BYTES) {
        evolve_fused_kernel<<<dim3(NB), dim3(1024), 0, stream>>>(pred, nodes, fnodes,
                                                                 gfield, counter);
    } else {
        evolve_direct_kernel<<<dim3(NB), dim3(64), 0, stream>>>(pred, nodes, fnodes, counter);
    }
    render_kernel<<<dim3(RBLK, NB), dim3(256), 0, stream>>>(pred, fnodes, partials,
                                                            counter, (float*)d_out);
}

// Round 6
// 65.107 us; speedup vs baseline: 1.0924x; 1.0207x over previous
//
#include <hip/hip_runtime.h>

// Problem constants (match reference)
#define HH 256
#define WW 256
#define NB 2
#define NN 128
#define NSTEPS_K 50
#define RBLK ((HH * WW) / 256)   // 256 render blocks per batch
#define NPART (NB * RBLK)        // 512 partials

// ws layout (floats):
//   [0 .. 511]     partials
//   [512 .. 1023]  final nodes (2*128*2)
//   [1024]         counter (int; zeroed by gradq/evolve_direct kernel)
//   [2048 .. ]     quad field: NB*HH*WW cells * 2 float4 (32B/cell, 2MB/batch)
#define WS_QUAD_OFF_F 2048
#define WS_NEEDED_BYTES ((WS_QUAD_OFF_F + (size_t)NB * HH * WW * 8) * 4)

// ---------------- quad-field precompute (massively parallel) -----------------
// For each cell (i,j): pack (gy,gx) of the 4 bilerp corners (i,j),(i,j+1),
// (i+1,j),(i+1,j+1) into 2 float4 = one 32B-aligned block -> the evolve loop
// samples with exactly 2 dwordx4 from ONE 64B line per node.
// Gradient math identical to jnp.gradient (bit-exact, validated rounds 2-5).
__device__ __forceinline__ float gy_at(const float* __restrict__ f, int i, int j) {
    int iu = max(i - 1, 0), id = min(i + 1, HH - 1);
    float s = (i == 0 || i == HH - 1) ? 1.0f : 0.5f;
    return s * (f[(id << 8) + j] - f[(iu << 8) + j]);
}
__device__ __forceinline__ float gx_at(const float* __restrict__ f, int i, int j) {
    int jl = max(j - 1, 0), jr = min(j + 1, WW - 1);
    float s = (j == 0 || j == WW - 1) ? 1.0f : 0.5f;
    return s * (f[(i << 8) + jr] - f[(i << 8) + jl]);
}

__global__ void gradq_kernel(const float* __restrict__ pred,
                             float4* __restrict__ q,
                             int* __restrict__ counter) {
    if (blockIdx.x == 0 && threadIdx.x == 0) {
        __hip_atomic_store(counter, 0, __ATOMIC_RELAXED, __HIP_MEMORY_SCOPE_AGENT);
    }
    const int gid = blockIdx.x * 256 + threadIdx.x;  // b*65536 + i*256 + j
    const int b = gid >> 16;
    const int p = gid & 0xFFFF;
    const int i = p >> 8, j = p & (WW - 1);
    const float* f = pred + (b << 16);
    const int i1 = min(i + 1, HH - 1);   // clamped; (i==255 / j==255) quads unused
    const int j1 = min(j + 1, WW - 1);
    float4 q0, q1;
    q0.x = gy_at(f, i, j);   q0.y = gx_at(f, i, j);
    q0.z = gy_at(f, i, j1);  q0.w = gx_at(f, i, j1);
    q1.x = gy_at(f, i1, j);  q1.y = gx_at(f, i1, j);
    q1.z = gy_at(f, i1, j1); q1.w = gx_at(f, i1, j1);
    q[(size_t)(gid << 1)] = q0;
    q[(size_t)(gid << 1) + 1] = q1;
}

// ---------------- evolve: 1 wave/batch, nodes in registers -------------------
// Lane l owns nodes 2l, 2l+1. Single shuffle round per step (neighbor
// POSITIONS), neighbors' d2 recomputed locally -> bit-exact two-stage d2/d4.
// Bilerp = 2 x dwordx4 per node from one 64B-aligned quad line.
__global__ __launch_bounds__(64, 1) void evolve3_kernel(
        const float4* __restrict__ q,
        const float* __restrict__ nodes_in,
        float* __restrict__ nodes_out) {
    const int b = blockIdx.x;
    const int l = threadIdx.x;            // 0..63
    const float4* qb = q + ((size_t)b << 17);   // 2 float4 per cell
    const int pl = (l + 63) & 63;
    const int nl = (l + 1) & 63;

    float4 nd = ((const float4*)nodes_in)[b * 64 + l];
    float y0n = nd.x, x0n = nd.y;         // node 2l
    float y1n = nd.z, x1n = nd.w;         // node 2l+1

    for (int s = 0; s < NSTEPS_K; ++s) {
        // ---- issue quad loads first (4 x dwordx4, 1 line per node) ----
        float yca = fminf(fmaxf(y0n, 0.0f), 254.999f);
        float xca = fminf(fmaxf(x0n, 0.0f), 254.999f);
        int ra = (int)yca, ca = (int)xca;
        float wya = yca - (float)ra, wxa = xca - (float)ca;
        int basea = ((ra << 8) + ca) << 1;
        float4 qa0 = qb[basea], qa1 = qb[basea + 1];

        float ycb = fminf(fmaxf(y1n, 0.0f), 254.999f);
        float xcb = fminf(fmaxf(x1n, 0.0f), 254.999f);
        int rb = (int)ycb, cb = (int)xcb;
        float wyb = ycb - (float)rb, wxb = xcb - (float)cb;
        int baseb = ((rb << 8) + cb) << 1;
        float4 qb0 = qb[baseb], qb1 = qb[baseb + 1];

        // ---- single shuffle round: neighbor positions ----
        float pya = __shfl(y0n, pl), pxa = __shfl(x0n, pl);   // node 2l-2
        float pyb = __shfl(y1n, pl), pxb = __shfl(x1n, pl);   // node 2l-1
        float nya = __shfl(y0n, nl), nxa = __shfl(x0n, nl);   // node 2l+2
        float nyb = __shfl(y1n, nl), nxb = __shfl(x1n, nl);   // node 2l+3

        // d2[i] = (x[i+1] + x[i-1]) - 2 x[i]
        float d2ya = (y1n + pyb) - 2.0f * y0n;   // d2 of 2l
        float d2xa = (x1n + pxb) - 2.0f * x0n;
        float d2yb = (nya + y0n) - 2.0f * y1n;   // d2 of 2l+1
        float d2xb = (nxa + x0n) - 2.0f * x1n;
        float d2pyb = (y0n + pya) - 2.0f * pyb;  // d2 of 2l-1
        float d2pxb = (x0n + pxa) - 2.0f * pxb;
        float d2nya = (nyb + y1n) - 2.0f * nya;  // d2 of 2l+2
        float d2nxa = (nxb + x1n) - 2.0f * nxa;

        // d4[i] = (d2[i+1] + d2[i-1]) - 2 d2[i]
        float d4ya = (d2yb + d2pyb) - 2.0f * d2ya;
        float d4xa = (d2xb + d2pxb) - 2.0f * d2xa;
        float d4yb = (d2nya + d2ya) - 2.0f * d2yb;
        float d4xb = (d2nxa + d2xa) - 2.0f * d2xb;

        // ---- bilerp (reference term order; quad comps = a00,a01 | a10,a11) ----
        float ua = 1.0f - wya, va = 1.0f - wxa;
        float bya = qa0.x * ua * va + qa0.z * ua * wxa + qa1.x * wya * va + qa1.z * wya * wxa;
        float bxa = qa0.y * ua * va + qa0.w * ua * wxa + qa1.y * wya * va + qa1.w * wya * wxa;
        float ub = 1.0f - wyb, vb = 1.0f - wxb;
        float byb = qb0.x * ub * vb + qb0.z * ub * wxb + qb1.x * wyb * vb + qb1.z * wyb * wxb;
        float bxb = qb0.y * ub * vb + qb0.w * ub * wxb + qb1.y * wyb * vb + qb1.w * wyb * wxb;

        // x += STEPSZ*(ALPHA*d2 - BETA*d4 + ext); clip [0,255]
        y0n = y0n + 0.1f * ((0.01f * d2ya - 0.01f * d4ya) + (-10.0f * bya));
        x0n = x0n + 0.1f * ((0.01f * d2xa - 0.01f * d4xa) + (-10.0f * bxa));
        y1n = y1n + 0.1f * ((0.01f * d2yb - 0.01f * d4yb) + (-10.0f * byb));
        x1n = x1n + 0.1f * ((0.01f * d2xb - 0.01f * d4xb) + (-10.0f * bxb));
        y0n = fminf(fmaxf(y0n, 0.0f), 255.0f);
        x0n = fminf(fmaxf(x0n, 0.0f), 255.0f);
        y1n = fminf(fmaxf(y1n, 0.0f), 255.0f);
        x1n = fminf(fmaxf(x1n, 0.0f), 255.0f);
    }

    float4 out; out.x = y0n; out.y = x0n; out.z = y1n; out.w = x1n;
    ((float4*)nodes_out)[b * 64 + l] = out;
}

// ---------------- fallback evolve (direct pred sampling; ws too small) -------
__device__ __forceinline__ void sample_grad_direct(const float* __restrict__ f,
                                                   float y, float x,
                                                   float& by, float& bx) {
    float yc = fminf(fmaxf(y, 0.0f), 254.999f);
    float xc = fminf(fmaxf(x, 0.0f), 254.999f);
    int r0 = (int)yc, c0 = (int)xc;
    int r1 = r0 + 1, c1 = c0 + 1;
    float wy = yc - (float)r0, wx = xc - (float)c0;
    int rm = max(r0 - 1, 0), rp = min(r1 + 1, HH - 1);
    int cm = max(c0 - 1, 0), cp = min(c1 + 1, WW - 1);
    float sy0 = (r0 == 0) ? 1.0f : 0.5f;
    float sy1 = (r1 == HH - 1) ? 1.0f : 0.5f;
    float sx0 = (c0 == 0) ? 1.0f : 0.5f;
    float sx1 = (c1 == WW - 1) ? 1.0f : 0.5f;
    const float* fr0 = f + (r0 << 8);
    const float* fr1 = f + (r1 << 8);
    const float* frm = f + (rm << 8);
    const float* frp = f + (rp << 8);
    float f00 = fr0[c0], f01 = fr0[c1];
    float f10 = fr1[c0], f11 = fr1[c1];
    float f0m = fr0[cm], f0p = fr0[cp];
    float f1m = fr1[cm], f1p = fr1[cp];
    float fm0 = frm[c0], fm1 = frm[c1];
    float fp0 = frp[c0], fp1 = frp[c1];
    float gy00 = sy0 * (f10 - fm0), gy01 = sy0 * (f11 - fm1);
    float gy10 = sy1 * (fp0 - f00), gy11 = sy1 * (fp1 - f01);
    float gx00 = sx0 * (f01 - f0m), gx01 = sx1 * (f0p - f00);
    float gx10 = sx0 * (f11 - f1m), gx11 = sx1 * (f1p - f10);
    float u = 1.0f - wy, v = 1.0f - wx;
    by = gy00 * u * v + gy01 * u * wx + gy10 * wy * v + gy11 * wy * wx;
    bx = gx00 * u * v + gx01 * u * wx + gx10 * wy * v + gx11 * wy * wx;
}

__global__ __launch_bounds__(64, 1) void evolve_direct_kernel(
        const float* __restrict__ pred,
        const float* __restrict__ nodes_in,
        float* __restrict__ nodes_out,
        int* __restrict__ counter) {
    const int b = blockIdx.x;
    const int l = threadIdx.x;
    if (b == 0 && l == 0) {
        __hip_atomic_store(counter, 0, __ATOMIC_RELAXED, __HIP_MEMORY_SCOPE_AGENT);
    }
    const float* f = pred + b * HH * WW;
    const int pl = (l + 63) & 63;
    const int nl = (l + 1) & 63;
    float4 nd = ((const float4*)nodes_in)[b * 64 + l];
    float y0n = nd.x, x0n = nd.y, y1n = nd.z, x1n = nd.w;
    for (int s = 0; s < NSTEPS_K; ++s) {
        float by0, bx0, by1, bx1;
        sample_grad_direct(f, y0n, x0n, by0, bx0);
        sample_grad_direct(f, y1n, x1n, by1, bx1);
        float pya = __shfl(y0n, pl), pxa = __shfl(x0n, pl);
        float pyb = __shfl(y1n, pl), pxb = __shfl(x1n, pl);
        float nya = __shfl(y0n, nl), nxa = __shfl(x0n, nl);
        float nyb = __shfl(y1n, nl), nxb = __shfl(x1n, nl);
        float d2ya = (y1n + pyb) - 2.0f * y0n;
        float d2xa = (x1n + pxb) - 2.0f * x0n;
        float d2yb = (nya + y0n) - 2.0f * y1n;
        float d2xb = (nxa + x0n) - 2.0f * x1n;
        float d2pyb = (y0n + pya) - 2.0f * pyb;
        float d2pxb = (x0n + pxa) - 2.0f * pxb;
        float d2nya = (nyb + y1n) - 2.0f * nya;
        float d2nxa = (nxb + x1n) - 2.0f * nxa;
        float d4ya = (d2yb + d2pyb) - 2.0f * d2ya;
        float d4xa = (d2xb + d2pxb) - 2.0f * d2xa;
        float d4yb = (d2nya + d2ya) - 2.0f * d2yb;
        float d4xb = (d2nxa + d2xa) - 2.0f * d2xb;
        y0n = y0n + 0.1f * ((0.01f * d2ya - 0.01f * d4ya) + (-10.0f * by0));
        x0n = x0n + 0.1f * ((0.01f * d2xa - 0.01f * d4xa) + (-10.0f * bx0));
        y1n = y1n + 0.1f * ((0.01f * d2yb - 0.01f * d4yb) + (-10.0f * by1));
        x1n = x1n + 0.1f * ((0.01f * d2xb - 0.01f * d4xb) + (-10.0f * bx1));
        y0n = fminf(fmaxf(y0n, 0.0f), 255.0f);
        x0n = fminf(fmaxf(x0n, 0.0f), 255.0f);
        y1n = fminf(fmaxf(y1n, 0.0f), 255.0f);
        x1n = fminf(fmaxf(x1n, 0.0f), 255.0f);
    }
    float4 out; out.x = y0n; out.y = x0n; out.z = y1n; out.w = x1n;
    ((float4*)nodes_out)[b * 64 + l] = out;
}

// ---------------- render + deterministic last-block finalize -----------------
__global__ void render_kernel(const float* __restrict__ pred,
                              const float* __restrict__ nodes,
                              float* __restrict__ partials,
                              int* __restrict__ counter,
                              float* __restrict__ out) {
    const int b = blockIdx.y;
    const int chunk = blockIdx.x;    // 0..255
    const int tid = threadIdx.x;     // 0..255

    __shared__ float p0y[NN], p0x[NN], sdy[NN], sdx[NN], sidd[NN];
    if (tid < NN) {
        float ay = nodes[(b * NN + tid) * 2 + 0];
        float ax = nodes[(b * NN + tid) * 2 + 1];
        int j = (tid + 1) & (NN - 1);
        float cy = nodes[(b * NN + j) * 2 + 0];
        float cx = nodes[(b * NN + j) * 2 + 1];
        float ddy = cy - ay, ddx = cx - ax;
        p0y[tid] = ay; p0x[tid] = ax;
        sdy[tid] = ddy; sdx[tid] = ddx;
        sidd[tid] = 1.0f / (ddy * ddy + ddx * ddx + 1e-8f);
    }
    __syncthreads();

    const int pix = chunk * 256 + tid;
    const float qy = (float)(pix >> 8);
    const float qx = (float)(pix & (WW - 1));

    float minr2 = 1e30f;
#pragma unroll 8
    for (int s = 0; s < NN; ++s) {
        float qpy = qy - p0y[s];
        float qpx = qx - p0x[s];
        float t = (qpy * sdy[s] + qpx * sdx[s]) * sidd[s];
        t = fminf(fmaxf(t, 0.0f), 1.0f);
        float ry = qpy - t * sdy[s];
        float rx = qpx - t * sdx[s];
        float r2 = ry * ry + rx * rx;
        minr2 = fminf(minr2, r2);
    }
    float dist = fminf(sqrtf(minr2 + 1e-12f), 15.0f);
    float e = pred[b * HH * WW + pix] - dist;
    float se = e * e;

    for (int off = 32; off > 0; off >>= 1) se += __shfl_down(se, off);
    __shared__ float red[4];
    if ((tid & 63) == 0) red[tid >> 6] = se;
    __syncthreads();

    __shared__ int lastBlk;
    if (tid == 0) {
        float p = (red[0] + red[1]) + (red[2] + red[3]);
        __hip_atomic_store(&partials[b * RBLK + chunk], p,
                           __ATOMIC_RELEASE, __HIP_MEMORY_SCOPE_AGENT);
        int t = __hip_atomic_fetch_add(counter, 1,
                                       __ATOMIC_ACQ_REL, __HIP_MEMORY_SCOPE_AGENT);
        lastBlk = (t == NPART - 1);
    }
    __syncthreads();

    if (lastBlk) {   // fixed-order tree sum -> bit-deterministic regardless of which block is last
        float v = __hip_atomic_load(&partials[tid], __ATOMIC_RELAXED, __HIP_MEMORY_SCOPE_AGENT)
                + __hip_atomic_load(&partials[tid + 256], __ATOMIC_RELAXED, __HIP_MEMORY_SCOPE_AGENT);
        for (int off = 32; off > 0; off >>= 1) v += __shfl_down(v, off);
        __shared__ float red2[4];
        if ((tid & 63) == 0) red2[tid >> 6] = v;
        __syncthreads();
        if (tid == 0)
            out[0] = ((red2[0] + red2[1]) + (red2[2] + red2[3]))
                     * (1.0f / (float)(NB * HH * WW));
    }
}

extern "C" void kernel_launch(void* const* d_in, const int* in_sizes, int n_in,
                              void* d_out, int out_size, void* d_ws, size_t ws_size,
                              hipStream_t stream) {
    const float* pred = (const float*)d_in[0];    // (B,1,H,W) f32
    const float* nodes = (const float*)d_in[1];   // (B,N,2) f32
    float* ws = (float*)d_ws;
    float* partials = ws;                 // 512 f
    float* fnodes = ws + 512;             // 512 f
    int* counter = (int*)(ws + 1024);     // 1 int (zeroed by first kernel)
    float4* quad = (float4*)(ws + WS_QUAD_OFF_F);

    if (ws_size >= WS_NEEDED_BYTES) {
        gradq_kernel<<<dim3(NB * HH * WW / 256), dim3(256), 0, stream>>>(pred, quad, counter);
        evolve3_kernel<<<dim3(NB), dim3(64), 0, stream>>>(quad, nodes, fnodes);
    } else {
        evolve_direct_kernel<<<dim3(NB), dim3(64), 0, stream>>>(pred, nodes, fnodes, counter);
    }
    render_kernel<<<dim3(RBLK, NB), dim3(256), 0, stream>>>(pred, fnodes, partials,
                                                            counter, (float*)d_out);
}

// Round 7
// 60.121 us; speedup vs baseline: 1.1830x; 1.0829x over previous
//
#include <hip/hip_runtime.h>

// Problem constants (match reference)
#define HH 256
#define WW 256
#define NB 2
#define NN 128
#define NSTEPS_K 50
#define RBLK ((HH * WW) / 256)   // 256 render blocks per batch
#define NPART (NB * RBLK)        // 512 partials

// ws layout (floats):
//   [0 .. 511]     partials
//   [512 .. 1023]  final nodes (2*128*2)
//   [1024]         counter (int; zeroed by grad/evolve_direct kernel)
//   [2048 .. ]     gradient field: NB*HH*WW float2 (512KB/batch)
#define WS_GRAD_OFF_F 2048
#define WS_NEEDED_BYTES ((WS_GRAD_OFF_F + (size_t)NB * HH * WW * 2) * 4)

// ---------------- gradient-field precompute (massively parallel) -------------
// Also zeroes the render completion counter (replaces a costly memset node).
__global__ void grad_kernel(const float* __restrict__ pred,
                            float2* __restrict__ g,
                            int* __restrict__ counter) {
    if (blockIdx.x == 0 && threadIdx.x == 0) {
        __hip_atomic_store(counter, 0, __ATOMIC_RELAXED, __HIP_MEMORY_SCOPE_AGENT);
    }
    const int idx = blockIdx.x * 256 + threadIdx.x;  // 0 .. NB*H*W-1
    const int b = idx >> 16;
    const int pix = idx & 0xFFFF;
    const int i = pix >> 8, j = pix & (WW - 1);
    const float* f = pred + (b << 16);
    int iu = max(i - 1, 0), id = min(i + 1, HH - 1);
    int jl = max(j - 1, 0), jr = min(j + 1, WW - 1);
    float sy = (i == 0 || i == HH - 1) ? 1.0f : 0.5f;
    float sx = (j == 0 || j == WW - 1) ? 1.0f : 0.5f;
    float gy = sy * (f[(id << 8) + j] - f[(iu << 8) + j]);
    float gx = sx * (f[(i << 8) + jr] - f[(i << 8) + jl]);
    g[idx] = make_float2(gy, gx);
}

// ---------------- evolve with in-kernel L2 warm ------------------------------
// NB blocks x 1024 threads. Phase A: all 16 waves READ every 64B line of this
// batch's 512KB field -> lines allocate in the LOCAL XCD L2 (the serial loop's
// scattered loads then hit L2 at ~250cy instead of L3/HBM at ~600-900cy).
// Phase B: wave 0 runs the 50 serial steps BIT-IDENTICALLY to round 4's
// evolve2 (absmax 0.0 validated) -- do not reassociate.
__global__ __launch_bounds__(1024, 1) void evolve_warm_kernel(
        const float2* __restrict__ g,
        const float* __restrict__ nodes_in,
        float* __restrict__ nodes_out) {
    const int b = blockIdx.x;
    const int tid = threadIdx.x;          // 0..1023
    const float2* gb = g + (b << 16);

    // ---- Phase A: touch all 8192 cache lines (8 cells of 8B per line) ----
    float acc = 0.0f;
    #pragma unroll
    for (int k = 0; k < 8; ++k) {
        int line = (k << 10) + tid;       // 0..8191
        float2 v = gb[line << 3];         // one 8B read per 64B line
        acc += v.x;
    }
    asm volatile("" :: "v"(acc));         // keep warm loads alive (no DCE)
    __syncthreads();
    if (tid >= 64) return;

    // ---- Phase B: 1 wave, lane l owns nodes 2l and 2l+1 in registers ----
    const int l = tid;                    // 0..63
    const int pl = (l + 63) & 63;
    const int nl = (l + 1) & 63;

    float4 nd = ((const float4*)nodes_in)[b * 64 + l];
    float y0n = nd.x, x0n = nd.y;         // node 2l
    float y1n = nd.z, x1n = nd.w;         // node 2l+1

    for (int s = 0; s < NSTEPS_K; ++s) {
        // ---- issue bilerp loads first (8 x dwordx2, local L2 hits) ----
        float yca = fminf(fmaxf(y0n, 0.0f), 254.999f);
        float xca = fminf(fmaxf(x0n, 0.0f), 254.999f);
        int ra = (int)yca, ca = (int)xca;
        float wya = yca - (float)ra, wxa = xca - (float)ca;
        int basea = (ra << 8) + ca;
        float2 a00 = gb[basea],       a01 = gb[basea + 1];
        float2 a10 = gb[basea + WW],  a11 = gb[basea + WW + 1];

        float ycb = fminf(fmaxf(y1n, 0.0f), 254.999f);
        float xcb = fminf(fmaxf(x1n, 0.0f), 254.999f);
        int rb = (int)ycb, cb = (int)xcb;
        float wyb = ycb - (float)rb, wxb = xcb - (float)cb;
        int baseb = (rb << 8) + cb;
        float2 b00 = gb[baseb],       b01 = gb[baseb + 1];
        float2 b10 = gb[baseb + WW],  b11 = gb[baseb + WW + 1];

        // ---- single shuffle round: neighbor positions ----
        float pya = __shfl(y0n, pl), pxa = __shfl(x0n, pl);   // node 2l-2
        float pyb = __shfl(y1n, pl), pxb = __shfl(x1n, pl);   // node 2l-1
        float nya = __shfl(y0n, nl), nxa = __shfl(x0n, nl);   // node 2l+2
        float nyb = __shfl(y1n, nl), nxb = __shfl(x1n, nl);   // node 2l+3

        // d2[i] = (x[i+1] + x[i-1]) - 2 x[i]
        float d2ya = (y1n + pyb) - 2.0f * y0n;   // d2 of 2l
        float d2xa = (x1n + pxb) - 2.0f * x0n;
        float d2yb = (nya + y0n) - 2.0f * y1n;   // d2 of 2l+1
        float d2xb = (nxa + x0n) - 2.0f * x1n;
        float d2pyb = (y0n + pya) - 2.0f * pyb;  // d2 of 2l-1
        float d2pxb = (x0n + pxa) - 2.0f * pxb;
        float d2nya = (nyb + y1n) - 2.0f * nya;  // d2 of 2l+2
        float d2nxa = (nxb + x1n) - 2.0f * nxa;

        // d4[i] = (d2[i+1] + d2[i-1]) - 2 d2[i]
        float d4ya = (d2yb + d2pyb) - 2.0f * d2ya;
        float d4xa = (d2xb + d2pxb) - 2.0f * d2xa;
        float d4yb = (d2nya + d2ya) - 2.0f * d2yb;
        float d4xb = (d2nxa + d2xa) - 2.0f * d2xb;

        // ---- bilerp (reference term order) ----
        float ua = 1.0f - wya, va = 1.0f - wxa;
        float bya = a00.x * ua * va + a01.x * ua * wxa + a10.x * wya * va + a11.x * wya * wxa;
        float bxa = a00.y * ua * va + a01.y * ua * wxa + a10.y * wya * va + a11.y * wya * wxa;
        float ub = 1.0f - wyb, vb = 1.0f - wxb;
        float byb = b00.x * ub * vb + b01.x * ub * wxb + b10.x * wyb * vb + b11.x * wyb * wxb;
        float bxb = b00.y * ub * vb + b01.y * ub * wxb + b10.y * wyb * vb + b11.y * wyb * wxb;

        // x += STEPSZ*(ALPHA*d2 - BETA*d4 + ext); clip [0,255]
        y0n = y0n + 0.1f * ((0.01f * d2ya - 0.01f * d4ya) + (-10.0f * bya));
        x0n = x0n + 0.1f * ((0.01f * d2xa - 0.01f * d4xa) + (-10.0f * bxa));
        y1n = y1n + 0.1f * ((0.01f * d2yb - 0.01f * d4yb) + (-10.0f * byb));
        x1n = x1n + 0.1f * ((0.01f * d2xb - 0.01f * d4xb) + (-10.0f * bxb));
        y0n = fminf(fmaxf(y0n, 0.0f), 255.0f);
        x0n = fminf(fmaxf(x0n, 0.0f), 255.0f);
        y1n = fminf(fmaxf(y1n, 0.0f), 255.0f);
        x1n = fminf(fmaxf(x1n, 0.0f), 255.0f);
    }

    float4 out; out.x = y0n; out.y = x0n; out.z = y1n; out.w = x1n;
    ((float4*)nodes_out)[b * 64 + l] = out;
}

// ---------------- fallback evolve (direct pred sampling; ws too small) -------
__device__ __forceinline__ void sample_grad_direct(const float* __restrict__ f,
                                                   float y, float x,
                                                   float& by, float& bx) {
    float yc = fminf(fmaxf(y, 0.0f), 254.999f);
    float xc = fminf(fmaxf(x, 0.0f), 254.999f);
    int r0 = (int)yc, c0 = (int)xc;
    int r1 = r0 + 1, c1 = c0 + 1;
    float wy = yc - (float)r0, wx = xc - (float)c0;
    int rm = max(r0 - 1, 0), rp = min(r1 + 1, HH - 1);
    int cm = max(c0 - 1, 0), cp = min(c1 + 1, WW - 1);
    float sy0 = (r0 == 0) ? 1.0f : 0.5f;
    float sy1 = (r1 == HH - 1) ? 1.0f : 0.5f;
    float sx0 = (c0 == 0) ? 1.0f : 0.5f;
    float sx1 = (c1 == WW - 1) ? 1.0f : 0.5f;
    const float* fr0 = f + (r0 << 8);
    const float* fr1 = f + (r1 << 8);
    const float* frm = f + (rm << 8);
    const float* frp = f + (rp << 8);
    float f00 = fr0[c0], f01 = fr0[c1];
    float f10 = fr1[c0], f11 = fr1[c1];
    float f0m = fr0[cm], f0p = fr0[cp];
    float f1m = fr1[cm], f1p = fr1[cp];
    float fm0 = frm[c0], fm1 = frm[c1];
    float fp0 = frp[c0], fp1 = frp[c1];
    float gy00 = sy0 * (f10 - fm0), gy01 = sy0 * (f11 - fm1);
    float gy10 = sy1 * (fp0 - f00), gy11 = sy1 * (fp1 - f01);
    float gx00 = sx0 * (f01 - f0m), gx01 = sx1 * (f0p - f00);
    float gx10 = sx0 * (f11 - f1m), gx11 = sx1 * (f1p - f10);
    float u = 1.0f - wy, v = 1.0f - wx;
    by = gy00 * u * v + gy01 * u * wx + gy10 * wy * v + gy11 * wy * wx;
    bx = gx00 * u * v + gx01 * u * wx + gx10 * wy * v + gx11 * wy * wx;
}

__global__ __launch_bounds__(64, 1) void evolve_direct_kernel(
        const float* __restrict__ pred,
        const float* __restrict__ nodes_in,
        float* __restrict__ nodes_out,
        int* __restrict__ counter) {
    const int b = blockIdx.x;
    const int l = threadIdx.x;
    if (b == 0 && l == 0) {
        __hip_atomic_store(counter, 0, __ATOMIC_RELAXED, __HIP_MEMORY_SCOPE_AGENT);
    }
    const float* f = pred + b * HH * WW;
    const int pl = (l + 63) & 63;
    const int nl = (l + 1) & 63;
    float4 nd = ((const float4*)nodes_in)[b * 64 + l];
    float y0n = nd.x, x0n = nd.y, y1n = nd.z, x1n = nd.w;
    for (int s = 0; s < NSTEPS_K; ++s) {
        float by0, bx0, by1, bx1;
        sample_grad_direct(f, y0n, x0n, by0, bx0);
        sample_grad_direct(f, y1n, x1n, by1, bx1);
        float pya = __shfl(y0n, pl), pxa = __shfl(x0n, pl);
        float pyb = __shfl(y1n, pl), pxb = __shfl(x1n, pl);
        float nya = __shfl(y0n, nl), nxa = __shfl(x0n, nl);
        float nyb = __shfl(y1n, nl), nxb = __shfl(x1n, nl);
        float d2ya = (y1n + pyb) - 2.0f * y0n;
        float d2xa = (x1n + pxb) - 2.0f * x0n;
        float d2yb = (nya + y0n) - 2.0f * y1n;
        float d2xb = (nxa + x0n) - 2.0f * x1n;
        float d2pyb = (y0n + pya) - 2.0f * pyb;
        float d2pxb = (x0n + pxa) - 2.0f * pxb;
        float d2nya = (nyb + y1n) - 2.0f * nya;
        float d2nxa = (nxb + x1n) - 2.0f * nxa;
        float d4ya = (d2yb + d2pyb) - 2.0f * d2ya;
        float d4xa = (d2xb + d2pxb) - 2.0f * d2xa;
        float d4yb = (d2nya + d2ya) - 2.0f * d2yb;
        float d4xb = (d2nxa + d2xa) - 2.0f * d2xb;
        y0n = y0n + 0.1f * ((0.01f * d2ya - 0.01f * d4ya) + (-10.0f * by0));
        x0n = x0n + 0.1f * ((0.01f * d2xa - 0.01f * d4xa) + (-10.0f * bx0));
        y1n = y1n + 0.1f * ((0.01f * d2yb - 0.01f * d4yb) + (-10.0f * by1));
        x1n = x1n + 0.1f * ((0.01f * d2xb - 0.01f * d4xb) + (-10.0f * bx1));
        y0n = fminf(fmaxf(y0n, 0.0f), 255.0f);
        x0n = fminf(fmaxf(x0n, 0.0f), 255.0f);
        y1n = fminf(fmaxf(y1n, 0.0f), 255.0f);
        x1n = fminf(fmaxf(x1n, 0.0f), 255.0f);
    }
    float4 out; out.x = y0n; out.y = x0n; out.z = y1n; out.w = x1n;
    ((float4*)nodes_out)[b * 64 + l] = out;
}

// ---------------- render + deterministic last-block finalize -----------------
__global__ void render_kernel(const float* __restrict__ pred,
                              const float* __restrict__ nodes,
                              float* __restrict__ partials,
                              int* __restrict__ counter,
                              float* __restrict__ out) {
    const int b = blockIdx.y;
    const int chunk = blockIdx.x;    // 0..255
    const int tid = threadIdx.x;     // 0..255

    __shared__ float p0y[NN], p0x[NN], sdy[NN], sdx[NN], sidd[NN];
    if (tid < NN) {
        float ay = nodes[(b * NN + tid) * 2 + 0];
        float ax = nodes[(b * NN + tid) * 2 + 1];
        int j = (tid + 1) & (NN - 1);
        float cy = nodes[(b * NN + j) * 2 + 0];
        float cx = nodes[(b * NN + j) * 2 + 1];
        float ddy = cy - ay, ddx = cx - ax;
        p0y[tid] = ay; p0x[tid] = ax;
        sdy[tid] = ddy; sdx[tid] = ddx;
        sidd[tid] = 1.0f / (ddy * ddy + ddx * ddx + 1e-8f);
    }
    __syncthreads();

    const int pix = chunk * 256 + tid;
    const float qy = (float)(pix >> 8);
    const float qx = (float)(pix & (WW - 1));

    float minr2 = 1e30f;
#pragma unroll 8
    for (int s = 0; s < NN; ++s) {
        float qpy = qy - p0y[s];
        float qpx = qx - p0x[s];
        float t = (qpy * sdy[s] + qpx * sdx[s]) * sidd[s];
        t = fminf(fmaxf(t, 0.0f), 1.0f);
        float ry = qpy - t * sdy[s];
        float rx = qpx - t * sdx[s];
        float r2 = ry * ry + rx * rx;
        minr2 = fminf(minr2, r2);
    }
    float dist = fminf(sqrtf(minr2 + 1e-12f), 15.0f);
    float e = pred[b * HH * WW + pix] - dist;
    float se = e * e;

    for (int off = 32; off > 0; off >>= 1) se += __shfl_down(se, off);
    __shared__ float red[4];
    if ((tid & 63) == 0) red[tid >> 6] = se;
    __syncthreads();

    __shared__ int lastBlk;
    if (tid == 0) {
        float p = (red[0] + red[1]) + (red[2] + red[3]);
        __hip_atomic_store(&partials[b * RBLK + chunk], p,
                           __ATOMIC_RELEASE, __HIP_MEMORY_SCOPE_AGENT);
        int t = __hip_atomic_fetch_add(counter, 1,
                                       __ATOMIC_ACQ_REL, __HIP_MEMORY_SCOPE_AGENT);
        lastBlk = (t == NPART - 1);
    }
    __syncthreads();

    if (lastBlk) {   // fixed-order tree sum -> bit-deterministic regardless of which block is last
        float v = __hip_atomic_load(&partials[tid], __ATOMIC_RELAXED, __HIP_MEMORY_SCOPE_AGENT)
                + __hip_atomic_load(&partials[tid + 256], __ATOMIC_RELAXED, __HIP_MEMORY_SCOPE_AGENT);
        for (int off = 32; off > 0; off >>= 1) v += __shfl_down(v, off);
        __shared__ float red2[4];
        if ((tid & 63) == 0) red2[tid >> 6] = v;
        __syncthreads();
        if (tid == 0)
            out[0] = ((red2[0] + red2[1]) + (red2[2] + red2[3]))
                     * (1.0f / (float)(NB * HH * WW));
    }
}

extern "C" void kernel_launch(void* const* d_in, const int* in_sizes, int n_in,
                              void* d_out, int out_size, void* d_ws, size_t ws_size,
                              hipStream_t stream) {
    const float* pred = (const float*)d_in[0];    // (B,1,H,W) f32
    const float* nodes = (const float*)d_in[1];   // (B,N,2) f32
    float* ws = (float*)d_ws;
    float* partials = ws;                 // 512 f
    float* fnodes = ws + 512;             // 512 f
    int* counter = (int*)(ws + 1024);     // 1 int (zeroed by first kernel)
    float2* gfield = (float2*)(ws + WS_GRAD_OFF_F);

    if (ws_size >= WS_NEEDED_BYTES) {
        grad_kernel<<<dim3(NB * HH * WW / 256), dim3(256), 0, stream>>>(pred, gfield, counter);
        evolve_warm_kernel<<<dim3(NB), dim3(1024), 0, stream>>>(gfield, nodes, fnodes);
    } else {
        evolve_direct_kernel<<<dim3(NB), dim3(64), 0, stream>>>(pred, nodes, fnodes, counter);
    }
    render_kernel<<<dim3(RBLK, NB), dim3(256), 0, stream>>>(pred, fnodes, partials,
                                                            counter, (float*)d_out);
}